// Round 6
// baseline (143.518 us; speedup 1.0000x reference)
//
#include <hip/hip_runtime.h>
#include <hip/hip_bf16.h>
#include <stdint.h>

#define NBATCH 16
#define SEQ 4096
#define DIM 256
#define MEM 40
#define KTOT 512            // interleaved K: k=2d -> x*W1, k=2d+1 -> h*W2
#define MTOT (NBATCH*SEQ)   // 65536 rows

typedef unsigned short u16;
typedef __attribute__((ext_vector_type(8))) short short8;
typedef __attribute__((ext_vector_type(4))) float f32x4;

typedef __attribute__((address_space(1))) const void gvoid_t;
typedef __attribute__((address_space(3))) void lvoid_t;

static __device__ __forceinline__ u16 f2bf(float f) {
    union { float f; uint32_t u; } v; v.f = f;
    uint32_t u = v.u;
    u += 0x7FFFu + ((u >> 16) & 1);   // RTNE (finite values only)
    return (u16)(u >> 16);
}

// ---------------------------------------------------------------------------
// Build B^T (bf16) with interleaved K: BmT32[n*256 + d] = pack(W1[d][n], W2[d][n])
// ---------------------------------------------------------------------------
__global__ __launch_bounds__(256) void k_bmat(const float* __restrict__ W1,
                                              const float* __restrict__ W2,
                                              uint32_t* __restrict__ BmT32) {
    const int n = blockIdx.x;
    const int d = threadIdx.x;
    float w1 = W1[d * DIM + n];
    float w2 = W2[d * DIM + n];
    BmT32[n * DIM + d] = (uint32_t)f2bf(w1) | ((uint32_t)f2bf(w2) << 16);
}

// ---------------------------------------------------------------------------
// FIR conv v5: LDS window (R4 structure) with fixed ratios.
// R4 failure: 11 LDS reads/output + VGPR=64 (no load-ahead ILP) + 43KB LDS
// (3 blocks/CU, 30% occ) -> latency-bound, 100us.
// v5: TBLK=64 -> LDS [104][64] f32 = 26.6KB -> 6 blocks/CU (24 waves);
// 8 outputs/chunk -> 48 reads / 8 outputs (6/output, FMA:LDS = 6.7:1);
// __launch_bounds__(256,5) -> VGPR cap ~102 so wp[40]+h[8]+c[8]+in-flight
// loads stay resident with room for ILP.
// ---------------------------------------------------------------------------
#define CGRP 64
#define TBLK 64
#define THALO (TBLK + MEM)   // 104 rows

template <bool GUARD>
__device__ __forceinline__ void stage_x(const float* __restrict__ xbase,
                                        float* __restrict__ xs,
                                        int t0, int tid) {
    float2* xs2 = (float2*)xs;
    if (!GUARD) {
        const float* src = xbase + (size_t)(t0 - MEM) * DIM;
#pragma unroll
        for (int k = 0; k < (THALO * CGRP / 2) / 256; ++k) {   // 13
            int f = tid + k * 256;
            int row = f >> 5, c2 = f & 31;
            xs2[f] = *(const float2*)(src + (size_t)row * DIM + c2 * 2);
        }
    } else {
#pragma unroll
        for (int k = 0; k < (THALO * CGRP / 2) / 256; ++k) {
            int f = tid + k * 256;
            int row = f >> 5, c2 = f & 31;
            int t = t0 - MEM + row;
            float2 v = make_float2(0.f, 0.f);
            if (t >= 0) v = *(const float2*)(xbase + (size_t)t * DIM + c2 * 2);
            xs2[f] = v;
        }
    }
}

__global__ __launch_bounds__(256, 5) void k_conv(const float* __restrict__ x,
                                                 const float* __restrict__ mw,
                                                 uint32_t* __restrict__ Aout,
                                                 float* __restrict__ total) {
    __shared__ float xs[THALO * CGRP];          // [row][c], row 0 == t0-40

    const int tid = threadIdx.x;
    const int b   = blockIdx.y;
    const int dg  = blockIdx.z;
    const int t0  = blockIdx.x * TBLK;
    const int d0  = dg * CGRP;

    const float* xbase = x + (size_t)b * SEQ * DIM + d0;
    if (t0 >= MEM) stage_x<false>(xbase, xs, t0, tid);
    else           stage_x<true >(xbase, xs, t0, tid);

    const int c    = tid & (CGRP - 1);   // lane == channel -> coalesced I/O
    const int tseg = tid >> 6;           // 4 segments of 16 timesteps
    const int d    = d0 + c;

    const float mw0 = mw[d];
    float wp[MEM];
#pragma unroll
    for (int l = 0; l < MEM; ++l) wp[l] = mw[(l + 1) * DIM + d] - mw0;

    __syncthreads();

    uint32_t* Ab = Aout + ((size_t)b * SEQ + t0 + tseg * 16) * DIM + d;
    const float* seg = xs + (size_t)(tseg * 16) * CGRP + c;   // j=0 row

    float colsum = 0.0f;
#pragma unroll
    for (int ch8 = 0; ch8 < 2; ++ch8) {          // 2 chunks of 8 outputs
        const float* pw = seg + (size_t)(ch8 * 8) * CGRP;
        float h[8] = {0.f, 0.f, 0.f, 0.f, 0.f, 0.f, 0.f, 0.f};
        float cc[8];
#pragma unroll
        for (int j = 0; j < MEM + 8; ++j) {      // 48 static-offset LDS reads
            float v = pw[(size_t)j * CGRP];
            const int moff = j - MEM;
#pragma unroll
            for (int i = 0; i < 8; ++i) {
                const int l = i - moff;          // tap index for output i
                if (l == 0) cc[i] = v;
                else if (l >= 1 && l <= MEM) h[i] = fmaf(wp[l - 1], v, h[i]);
            }
        }
#pragma unroll
        for (int i = 0; i < 8; ++i) colsum += cc[i];
#pragma unroll
        for (int i = 0; i < 8; ++i) {
            __hip_bfloat162 p = __float22bfloat162_rn(make_float2(cc[i], h[i]));
            Ab[(size_t)(ch8 * 8 + i) * DIM] = *reinterpret_cast<uint32_t*>(&p);
        }
    }
    atomicAdd(&total[b * DIM + d], colsum);
}

// ---------------------------------------------------------------------------
// corr[b][n] = bias[n] + sum_d mw[0][d] * total[b][d] * W2[d][n]
// ---------------------------------------------------------------------------
__global__ __launch_bounds__(256) void k_corr(const float* __restrict__ W2,
                                              const float* __restrict__ bias,
                                              const float* __restrict__ mw,
                                              const float* __restrict__ total,
                                              float* __restrict__ corr) {
    const int b = blockIdx.x;
    const int n = threadIdx.x;
    float s = bias[n];
    for (int dd = 0; dd < DIM; ++dd)
        s += mw[dd] * total[b * DIM + dd] * W2[dd * DIM + n];
    corr[b * DIM + n] = s;
}

// ---------------------------------------------------------------------------
// GEMM: out[M=65536, N=256] = A[M, 512](bf16) @ Bmat[512, 256](bf16) + corr[b]
// BM=128, BN=256, BK=64, 8 waves, 16x16x32 MFMA. XCD-aware bijective swizzle
// (512 blocks, 512%8==0) for L2 locality on the memory-bound A stream.
// ---------------------------------------------------------------------------
#define BM 128
#define BN 256
#define BK 64

__global__ __launch_bounds__(512) void k_gemm(const u16* A,
                                              const u16* __restrict__ BmT,
                                              const float* __restrict__ corr,
                                              float* out) {
    __shared__ __align__(16) u16 Alds[BM * BK];   // 16 KB, [row][k]
    __shared__ __align__(16) u16 Blds[BN * BK];   // 32 KB, [col][k]

    const int tid  = threadIdx.x;
    const int lane = tid & 63;
    const int w    = tid >> 6;     // 0..7
    const int wr   = w >> 2;       // 0..1  (M split)
    const int wc   = w & 3;        // 0..3  (N split)
    // XCD swizzle: 512 blocks -> 64 contiguous tiles per XCD
    const int bid  = blockIdx.x;
    const int swz  = (bid & 7) * 64 + (bid >> 3);
    const int m0   = swz * BM;

    f32x4 acc[4][4] = {};

    for (int kt = 0; kt < KTOT / BK; ++kt) {
        const int k0 = kt * BK;
        // ---- stage A tile [128][64] : 1024 x 16B chunks, 2 per thread
#pragma unroll
        for (int i = 0; i < 2; ++i) {
            int c   = i * 512 + tid;
            int row = c >> 3;
            int kin = (c & 7) * 8;
            const u16* g = A + ((size_t)(m0 + row) * KTOT + k0 + kin);
            char* l = (char*)Alds + (size_t)(i * 512 + (tid & ~63)) * 16;
            __builtin_amdgcn_global_load_lds((gvoid_t*)g, (lvoid_t*)l, 16, 0, 0);
        }
        // ---- stage B tile [256 cols][64 k] from BmT[n][k] : 2048 chunks, 4/thread
#pragma unroll
        for (int i = 0; i < 4; ++i) {
            int c   = i * 512 + tid;
            int n   = c >> 3;
            int kin = (c & 7) * 8;
            const u16* g = BmT + ((size_t)n * KTOT + k0 + kin);
            char* l = (char*)Blds + (size_t)(i * 512 + (tid & ~63)) * 16;
            __builtin_amdgcn_global_load_lds((gvoid_t*)g, (lvoid_t*)l, 16, 0, 0);
        }
        __syncthreads();

#pragma unroll
        for (int kk = 0; kk < 2; ++kk) {
            short8 af[4], bfr[4];
#pragma unroll
            for (int mi = 0; mi < 4; ++mi) {
                int r = wr * 64 + mi * 16 + (lane & 15);
                af[mi] = *(const short8*)(Alds + r * BK + kk * 32 + ((lane >> 4) * 8));
            }
#pragma unroll
            for (int ni = 0; ni < 4; ++ni) {
                int ccol = wc * 64 + ni * 16 + (lane & 15);
                bfr[ni] = *(const short8*)(Blds + ccol * BK + kk * 32 + ((lane >> 4) * 8));
            }
#pragma unroll
            for (int mi = 0; mi < 4; ++mi)
#pragma unroll
                for (int ni = 0; ni < 4; ++ni)
                    acc[mi][ni] = __builtin_amdgcn_mfma_f32_16x16x32_bf16(
                        af[mi], bfr[ni], acc[mi][ni], 0, 0, 0);
        }
        __syncthreads();
    }

    // ---- epilogue: out = acc + corr[b][col]
    const int bidx = m0 >> 12;           // 4096 rows per batch, BM=128 divides it
    const float* corr_b = corr + bidx * DIM;
#pragma unroll
    for (int ni = 0; ni < 4; ++ni) {
        int col = wc * 64 + ni * 16 + (lane & 15);
        float cv = corr_b[col];
#pragma unroll
        for (int mi = 0; mi < 4; ++mi) {
            int rbase = m0 + wr * 64 + mi * 16 + ((lane >> 4) * 4);
#pragma unroll
            for (int j = 0; j < 4; ++j)
                out[(size_t)(rbase + j) * DIM + col] = acc[mi][ni][j] + cv;
        }
    }
}

// ---------------------------------------------------------------------------
extern "C" void kernel_launch(void* const* d_in, const int* in_sizes, int n_in,
                              void* d_out, int out_size, void* d_ws, size_t ws_size,
                              hipStream_t stream) {
    const float* x    = (const float*)d_in[0];
    const float* W1   = (const float*)d_in[1];
    const float* W2   = (const float*)d_in[2];
    const float* bias = (const float*)d_in[3];
    const float* mw   = (const float*)d_in[4];
    float* out = (float*)d_out;

    // ws layout: BmT (256*512*2 = 256KB) | total (16KB) | corr (16KB)
    u16*   BmT   = (u16*)d_ws;
    float* total = (float*)((char*)d_ws + 262144);
    float* corr  = (float*)((char*)d_ws + 262144 + 16384);

    hipMemsetAsync(total, 0, NBATCH * DIM * sizeof(float), stream);
    k_bmat<<<dim3(DIM), dim3(256), 0, stream>>>(W1, W2, (uint32_t*)BmT);
    k_conv<<<dim3(SEQ / TBLK, NBATCH, DIM / CGRP), dim3(256), 0, stream>>>(
        x, mw, (uint32_t*)d_out, total);
    k_corr<<<dim3(NBATCH), dim3(256), 0, stream>>>(W2, bias, mw, total, corr);
    k_gemm<<<dim3(MTOT / BM), dim3(512), 0, stream>>>(
        (const u16*)d_out, BmT, corr, out);
}

// Round 7
// 94.449 us; speedup vs baseline: 1.5195x; 1.5195x over previous
//
#include <hip/hip_runtime.h>
#include <hip/hip_bf16.h>
#include <stdint.h>

#define NBATCH 16
#define SEQ 4096
#define DIM 256
#define MEM 40
#define KTOT 512            // interleaved K: k=2d -> x*W1, k=2d+1 -> h*W2
#define MTOT (NBATCH*SEQ)   // 65536 rows

typedef unsigned short u16;
typedef __attribute__((ext_vector_type(8))) short short8;
typedef __attribute__((ext_vector_type(4))) float f32x4;

typedef __attribute__((address_space(1))) const void gvoid_t;
typedef __attribute__((address_space(3))) void lvoid_t;

static __device__ __forceinline__ u16 f2bf(float f) {
    union { float f; uint32_t u; } v; v.f = f;
    uint32_t u = v.u;
    u += 0x7FFFu + ((u >> 16) & 1);   // RTNE (finite values only)
    return (u16)(u >> 16);
}

// ---------------------------------------------------------------------------
// Build B^T (bf16) with interleaved K: BmT32[n*256 + d] = pack(W1[d][n], W2[d][n])
// ---------------------------------------------------------------------------
__global__ __launch_bounds__(256) void k_bmat(const float* __restrict__ W1,
                                              const float* __restrict__ W2,
                                              uint32_t* __restrict__ BmT32) {
    const int n = blockIdx.x;
    const int d = threadIdx.x;
    float w1 = W1[d * DIM + n];
    float w2 = W2[d * DIM + n];
    BmT32[n * DIM + d] = (uint32_t)f2bf(w1) | ((uint32_t)f2bf(w2) << 16);
}

// ---------------------------------------------------------------------------
// FIR conv v6: 2-way tap split across lane halves.
// Failed designs: 1 thread/40 taps (R0/R1/R5: 80 live regs -> spill/remat at
// any VGPR target), 4-way lane split (R2: serial shfl handoff chain), window
// in global (R3: cache thrash) or LDS (R4/R5: ds_read latency-bound).
// v6: lane = c + 32g. g=0 owns taps 1..20 of channel c, g=1 owns taps 21..40
// == same sliding FIR with time shifted by 20 (fresh load = x[t-20]).
// Per-thread: wt[20]+hist[20]+cur[4]+h[4] ~= 62 regs -> fits 64, no spill.
// Cross-lane: ONE butterfly shfl_xor(32) per output (no serial chain).
// g=0 lanes pack bf16 (x|h) and store interleaved A; also accumulate colsum.
// ---------------------------------------------------------------------------
#define TW 64    // timesteps per wave

template <bool GUARD>
__device__ __forceinline__ void conv_wave(const float* __restrict__ xb,   // + d
                                          uint32_t* __restrict__ Ab,     // + d
                                          const float* __restrict__ mw,
                                          float* __restrict__ total,
                                          int d, int b, int t0, int g, bool lead) {
    const float mw0 = mw[d];
    float wt[20];
#pragma unroll
    for (int j = 0; j < 20; ++j)
        wt[j] = mw[(20 * g + j + 1) * DIM + d] - mw0;   // taps 20g+1 .. 20g+20

    const int tg = t0 - 20 * g;      // this group's local time origin
    float hist[20];                  // hist[m] = x[tg - 20 + m]
#pragma unroll
    for (int m = 0; m < 20; ++m) {
        int t = tg - 20 + m;
        if (GUARD)
            hist[m] = (t >= 0) ? xb[(size_t)t * DIM] : 0.0f;
        else
            hist[m] = xb[(size_t)t * DIM];
    }

    float colsum = 0.0f;
#pragma unroll
    for (int ch = 0; ch < TW / 4; ++ch) {      // 16 chunks of 4 outputs
        const int tb = tg + ch * 4;
        float cur[4];
#pragma unroll
        for (int i = 0; i < 4; ++i) {
            int tt = tb + i;
            if (GUARD)
                cur[i] = (tt >= 0) ? xb[(size_t)tt * DIM] : 0.0f;
            else
                cur[i] = xb[(size_t)tt * DIM];
        }
        // output i uses C[i .. i+19], C[m] = (m<20) ? hist[m] : cur[m-20]
        float h[4];
#pragma unroll
        for (int i = 0; i < 4; ++i) {
            float acc = 0.0f;
#pragma unroll
            for (int j = 0; j < 20; ++j) {       // tap 20g+1+j uses C[i+19-j]
                int m = i + 19 - j;
                float v = (m < 20) ? hist[m] : cur[m - 20];
                acc = fmaf(wt[j], v, acc);
            }
            h[i] = acc;
        }
#pragma unroll
        for (int i = 0; i < 4; ++i) {
            float hs = h[i] + __shfl_xor(h[i], 32, 64);
            if (lead) {
                colsum += cur[i];
                __hip_bfloat162 p = __float22bfloat162_rn(make_float2(cur[i], hs));
                Ab[(size_t)(t0 + ch * 4 + i) * DIM] = *reinterpret_cast<uint32_t*>(&p);
            }
        }
        // slide: new hist = [hist[4..19], cur[0..3]]
#pragma unroll
        for (int m = 0; m < 16; ++m) hist[m] = hist[m + 4];
#pragma unroll
        for (int i = 0; i < 4; ++i) hist[16 + i] = cur[i];
    }
    if (lead) atomicAdd(&total[b * DIM + d], colsum);
}

__global__ void k_conv(const float* __restrict__ x,
                       const float* __restrict__ mw,
                       uint32_t* __restrict__ Aout,
                       float* __restrict__ total) {
    const int tid  = threadIdx.x;
    const int lane = tid & 63;
    const int w    = tid >> 6;           // 4 waves
    const int c    = lane & 31;
    const int g    = lane >> 5;          // tap half
    const int d    = blockIdx.z * 128 + w * 32 + c;
    const int b    = blockIdx.y;
    const int t0   = blockIdx.x * TW;

    const float* xb = x + (size_t)b * SEQ * DIM + d;
    uint32_t* Ab    = Aout + (size_t)b * SEQ * DIM + d;

    if (blockIdx.x == 0)
        conv_wave<true >(xb, Ab, mw, total, d, b, t0, g, g == 0);
    else
        conv_wave<false>(xb, Ab, mw, total, d, b, t0, g, g == 0);
}

// ---------------------------------------------------------------------------
// corr[b][n] = bias[n] + sum_d mw[0][d] * total[b][d] * W2[d][n]
// ---------------------------------------------------------------------------
__global__ __launch_bounds__(256) void k_corr(const float* __restrict__ W2,
                                              const float* __restrict__ bias,
                                              const float* __restrict__ mw,
                                              const float* __restrict__ total,
                                              float* __restrict__ corr) {
    const int b = blockIdx.x;
    const int n = threadIdx.x;
    float s = bias[n];
    for (int dd = 0; dd < DIM; ++dd)
        s += mw[dd] * total[b * DIM + dd] * W2[dd * DIM + n];
    corr[b * DIM + n] = s;
}

// ---------------------------------------------------------------------------
// GEMM: out[M=65536, N=256] = A[M, 512](bf16) @ Bmat[512, 256](bf16) + corr[b]
// BM=128, BN=256, BK=64, 8 waves, 16x16x32 MFMA. XCD-aware bijective swizzle
// (512 blocks, 512%8==0) for L2 locality on the memory-bound A stream.
// ---------------------------------------------------------------------------
#define BM 128
#define BN 256
#define BK 64

__global__ __launch_bounds__(512) void k_gemm(const u16* A,
                                              const u16* __restrict__ BmT,
                                              const float* __restrict__ corr,
                                              float* out) {
    __shared__ __align__(16) u16 Alds[BM * BK];   // 16 KB, [row][k]
    __shared__ __align__(16) u16 Blds[BN * BK];   // 32 KB, [col][k]

    const int tid  = threadIdx.x;
    const int lane = tid & 63;
    const int w    = tid >> 6;     // 0..7
    const int wr   = w >> 2;       // 0..1  (M split)
    const int wc   = w & 3;        // 0..3  (N split)
    // XCD swizzle: 512 blocks -> 64 contiguous tiles per XCD
    const int bid  = blockIdx.x;
    const int swz  = (bid & 7) * 64 + (bid >> 3);
    const int m0   = swz * BM;

    f32x4 acc[4][4] = {};

    for (int kt = 0; kt < KTOT / BK; ++kt) {
        const int k0 = kt * BK;
        // ---- stage A tile [128][64] : 1024 x 16B chunks, 2 per thread
#pragma unroll
        for (int i = 0; i < 2; ++i) {
            int c   = i * 512 + tid;
            int row = c >> 3;
            int kin = (c & 7) * 8;
            const u16* g = A + ((size_t)(m0 + row) * KTOT + k0 + kin);
            char* l = (char*)Alds + (size_t)(i * 512 + (tid & ~63)) * 16;
            __builtin_amdgcn_global_load_lds((gvoid_t*)g, (lvoid_t*)l, 16, 0, 0);
        }
        // ---- stage B tile [256 cols][64 k] from BmT[n][k] : 2048 chunks, 4/thread
#pragma unroll
        for (int i = 0; i < 4; ++i) {
            int c   = i * 512 + tid;
            int n   = c >> 3;
            int kin = (c & 7) * 8;
            const u16* g = BmT + ((size_t)n * KTOT + k0 + kin);
            char* l = (char*)Blds + (size_t)(i * 512 + (tid & ~63)) * 16;
            __builtin_amdgcn_global_load_lds((gvoid_t*)g, (lvoid_t*)l, 16, 0, 0);
        }
        __syncthreads();

#pragma unroll
        for (int kk = 0; kk < 2; ++kk) {
            short8 af[4], bfr[4];
#pragma unroll
            for (int mi = 0; mi < 4; ++mi) {
                int r = wr * 64 + mi * 16 + (lane & 15);
                af[mi] = *(const short8*)(Alds + r * BK + kk * 32 + ((lane >> 4) * 8));
            }
#pragma unroll
            for (int ni = 0; ni < 4; ++ni) {
                int ccol = wc * 64 + ni * 16 + (lane & 15);
                bfr[ni] = *(const short8*)(Blds + ccol * BK + kk * 32 + ((lane >> 4) * 8));
            }
#pragma unroll
            for (int mi = 0; mi < 4; ++mi)
#pragma unroll
                for (int ni = 0; ni < 4; ++ni)
                    acc[mi][ni] = __builtin_amdgcn_mfma_f32_16x16x32_bf16(
                        af[mi], bfr[ni], acc[mi][ni], 0, 0, 0);
        }
        __syncthreads();
    }

    // ---- epilogue: out = acc + corr[b][col]
    const int bidx = m0 >> 12;           // 4096 rows per batch, BM=128 divides it
    const float* corr_b = corr + bidx * DIM;
#pragma unroll
    for (int ni = 0; ni < 4; ++ni) {
        int col = wc * 64 + ni * 16 + (lane & 15);
        float cv = corr_b[col];
#pragma unroll
        for (int mi = 0; mi < 4; ++mi) {
            int rbase = m0 + wr * 64 + mi * 16 + ((lane >> 4) * 4);
#pragma unroll
            for (int j = 0; j < 4; ++j)
                out[(size_t)(rbase + j) * DIM + col] = acc[mi][ni][j] + cv;
        }
    }
}

// ---------------------------------------------------------------------------
extern "C" void kernel_launch(void* const* d_in, const int* in_sizes, int n_in,
                              void* d_out, int out_size, void* d_ws, size_t ws_size,
                              hipStream_t stream) {
    const float* x    = (const float*)d_in[0];
    const float* W1   = (const float*)d_in[1];
    const float* W2   = (const float*)d_in[2];
    const float* bias = (const float*)d_in[3];
    const float* mw   = (const float*)d_in[4];
    float* out = (float*)d_out;

    // ws layout: BmT (256*512*2 = 256KB) | total (16KB) | corr (16KB)
    u16*   BmT   = (u16*)d_ws;
    float* total = (float*)((char*)d_ws + 262144);
    float* corr  = (float*)((char*)d_ws + 262144 + 16384);

    hipMemsetAsync(total, 0, NBATCH * DIM * sizeof(float), stream);
    k_bmat<<<dim3(DIM), dim3(256), 0, stream>>>(W1, W2, (uint32_t*)BmT);
    k_conv<<<dim3(SEQ / TW, NBATCH, 2), dim3(256), 0, stream>>>(
        x, mw, (uint32_t*)d_out, total);
    k_corr<<<dim3(NBATCH), dim3(256), 0, stream>>>(W2, bias, mw, total, corr);
    k_gemm<<<dim3(MTOT / BM), dim3(512), 0, stream>>>(
        (const u16*)d_out, BmT, corr, out);
}

// Round 8
// 87.315 us; speedup vs baseline: 1.6437x; 1.0817x over previous
//
#include <hip/hip_runtime.h>
#include <hip/hip_bf16.h>
#include <stdint.h>

#define NBATCH 16
#define SEQ 4096
#define DIM 256
#define MEM 40
#define KTOT 512            // interleaved K: k=2d -> x*W1, k=2d+1 -> h*W2
#define MTOT (NBATCH*SEQ)   // 65536 rows

typedef unsigned short u16;
typedef __attribute__((ext_vector_type(8))) short short8;
typedef __attribute__((ext_vector_type(4))) float f32x4;

typedef __attribute__((address_space(1))) const void gvoid_t;
typedef __attribute__((address_space(3))) void lvoid_t;

static __device__ __forceinline__ u16 f2bf(float f) {
    union { float f; uint32_t u; } v; v.f = f;
    uint32_t u = v.u;
    u += 0x7FFFu + ((u >> 16) & 1);   // RTNE (finite values only)
    return (u16)(u >> 16);
}

// ---------------------------------------------------------------------------
// Build B^T (bf16) with interleaved K: BmT32[n*256 + d] = pack(W1[d][n], W2[d][n])
// ---------------------------------------------------------------------------
__global__ __launch_bounds__(256) void k_bmat(const float* __restrict__ W1,
                                              const float* __restrict__ W2,
                                              uint32_t* __restrict__ BmT32) {
    const int n = blockIdx.x;
    const int d = threadIdx.x;
    float w1 = W1[d * DIM + n];
    float w2 = W2[d * DIM + n];
    BmT32[n * DIM + d] = (uint32_t)f2bf(w1) | ((uint32_t)f2bf(w2) << 16);
}

// ---------------------------------------------------------------------------
// FIR conv v7 = R6 (2-way tap split, VGPR-clean, FETCH-clean) + pipeline:
//  - prefetch next chunk's 4 x-loads (nxt[]) one chunk ahead -> HBM latency
//    hidden under chunk compute (R6 consumed loads in-chunk -> 29% VALUBusy)
//  - 20-tap chains split into 2x10 accumulators -> 2x FMA dep-chain ILP
// lane = c + 32g; g owns taps 20g+1..20g+20 of channel c (g=1 == same FIR
// time-shifted by 20). One shfl_xor(32) combines halves; g=0 packs/stores.
// ---------------------------------------------------------------------------
#define TW 64    // timesteps per wave

template <bool GUARD>
__device__ __forceinline__ void conv_wave(const float* __restrict__ xb,   // + d
                                          uint32_t* __restrict__ Ab,     // + d
                                          const float* __restrict__ mw,
                                          float* __restrict__ total,
                                          int d, int b, int t0, int g, bool lead) {
    const float mw0 = mw[d];
    float wt[20];
#pragma unroll
    for (int j = 0; j < 20; ++j)
        wt[j] = mw[(20 * g + j + 1) * DIM + d] - mw0;   // taps 20g+1 .. 20g+20

    const int tg = t0 - 20 * g;      // this group's local time origin
    float hist[20];                  // hist[m] = x[tg - 20 + m]
#pragma unroll
    for (int m = 0; m < 20; ++m) {
        int t = tg - 20 + m;
        hist[m] = (!GUARD || t >= 0) ? xb[(size_t)t * DIM] : 0.0f;
    }

    // prefetch chunk 0
    float nxt[4];
#pragma unroll
    for (int i = 0; i < 4; ++i) {
        int tt = tg + i;
        nxt[i] = (!GUARD || tt >= 0) ? xb[(size_t)tt * DIM] : 0.0f;
    }

    float colsum = 0.0f;
#pragma unroll
    for (int ch = 0; ch < TW / 4; ++ch) {      // 16 chunks of 4 outputs
        float cur[4];
#pragma unroll
        for (int i = 0; i < 4; ++i) cur[i] = nxt[i];
        if (ch < TW / 4 - 1) {                 // prefetch chunk ch+1
#pragma unroll
            for (int i = 0; i < 4; ++i) {
                int tt = tg + (ch + 1) * 4 + i;
                nxt[i] = (!GUARD || tt >= 0) ? xb[(size_t)tt * DIM] : 0.0f;
            }
        }
        // output i uses C[i .. i+19], C[m] = (m<20) ? hist[m] : cur[m-20]
        float h[4];
#pragma unroll
        for (int i = 0; i < 4; ++i) {
            float a0 = 0.0f, a1 = 0.0f;
#pragma unroll
            for (int j = 0; j < 10; ++j) {       // tap 20g+1+j uses C[i+19-j]
                int m = i + 19 - j;
                float v = (m < 20) ? hist[m] : cur[m - 20];
                a0 = fmaf(wt[j], v, a0);
            }
#pragma unroll
            for (int j = 10; j < 20; ++j) {
                int m = i + 19 - j;
                float v = (m < 20) ? hist[m] : cur[m - 20];
                a1 = fmaf(wt[j], v, a1);
            }
            h[i] = a0 + a1;
        }
#pragma unroll
        for (int i = 0; i < 4; ++i) {
            float hs = h[i] + __shfl_xor(h[i], 32, 64);
            if (lead) {
                colsum += cur[i];
                __hip_bfloat162 p = __float22bfloat162_rn(make_float2(cur[i], hs));
                Ab[(size_t)(t0 + ch * 4 + i) * DIM] = *reinterpret_cast<uint32_t*>(&p);
            }
        }
        // slide: new hist = [hist[4..19], cur[0..3]]
#pragma unroll
        for (int m = 0; m < 16; ++m) hist[m] = hist[m + 4];
#pragma unroll
        for (int i = 0; i < 4; ++i) hist[16 + i] = cur[i];
    }
    if (lead) atomicAdd(&total[b * DIM + d], colsum);
}

__global__ void k_conv(const float* __restrict__ x,
                       const float* __restrict__ mw,
                       uint32_t* __restrict__ Aout,
                       float* __restrict__ total) {
    const int tid  = threadIdx.x;
    const int lane = tid & 63;
    const int w    = tid >> 6;           // 4 waves
    const int c    = lane & 31;
    const int g    = lane >> 5;          // tap half
    const int d    = blockIdx.z * 128 + w * 32 + c;
    const int b    = blockIdx.y;
    const int t0   = blockIdx.x * TW;

    const float* xb = x + (size_t)b * SEQ * DIM + d;
    uint32_t* Ab    = Aout + (size_t)b * SEQ * DIM + d;

    if (blockIdx.x == 0)
        conv_wave<true >(xb, Ab, mw, total, d, b, t0, g, g == 0);
    else
        conv_wave<false>(xb, Ab, mw, total, d, b, t0, g, g == 0);
}

// ---------------------------------------------------------------------------
// corr[b][n] = bias[n] + sum_d mw[0][d] * total[b][d] * W2[d][n]
// ---------------------------------------------------------------------------
__global__ __launch_bounds__(256) void k_corr(const float* __restrict__ W2,
                                              const float* __restrict__ bias,
                                              const float* __restrict__ mw,
                                              const float* __restrict__ total,
                                              float* __restrict__ corr) {
    const int b = blockIdx.x;
    const int n = threadIdx.x;
    float s = bias[n];
    for (int dd = 0; dd < DIM; ++dd)
        s += mw[dd] * total[b * DIM + dd] * W2[dd * DIM + n];
    corr[b * DIM + n] = s;
}

// ---------------------------------------------------------------------------
// GEMM: out[M=65536, N=256] = A[M, 512](bf16) @ Bmat[512, 256](bf16) + corr[b]
// BM=128, BN=256, BK=64, 8 waves, 16x16x32 MFMA. XCD-aware bijective swizzle
// (512 blocks, 512%8==0) for L2 locality on the memory-bound A stream.
// ---------------------------------------------------------------------------
#define BM 128
#define BN 256
#define BK 64

__global__ __launch_bounds__(512) void k_gemm(const u16* A,
                                              const u16* __restrict__ BmT,
                                              const float* __restrict__ corr,
                                              float* out) {
    __shared__ __align__(16) u16 Alds[BM * BK];   // 16 KB, [row][k]
    __shared__ __align__(16) u16 Blds[BN * BK];   // 32 KB, [col][k]

    const int tid  = threadIdx.x;
    const int lane = tid & 63;
    const int w    = tid >> 6;     // 0..7
    const int wr   = w >> 2;       // 0..1  (M split)
    const int wc   = w & 3;        // 0..3  (N split)
    // XCD swizzle: 512 blocks -> 64 contiguous tiles per XCD
    const int bid  = blockIdx.x;
    const int swz  = (bid & 7) * 64 + (bid >> 3);
    const int m0   = swz * BM;

    f32x4 acc[4][4] = {};

    for (int kt = 0; kt < KTOT / BK; ++kt) {
        const int k0 = kt * BK;
        // ---- stage A tile [128][64] : 1024 x 16B chunks, 2 per thread
#pragma unroll
        for (int i = 0; i < 2; ++i) {
            int c   = i * 512 + tid;
            int row = c >> 3;
            int kin = (c & 7) * 8;
            const u16* g = A + ((size_t)(m0 + row) * KTOT + k0 + kin);
            char* l = (char*)Alds + (size_t)(i * 512 + (tid & ~63)) * 16;
            __builtin_amdgcn_global_load_lds((gvoid_t*)g, (lvoid_t*)l, 16, 0, 0);
        }
        // ---- stage B tile [256 cols][64 k] from BmT[n][k] : 2048 chunks, 4/thread
#pragma unroll
        for (int i = 0; i < 4; ++i) {
            int c   = i * 512 + tid;
            int n   = c >> 3;
            int kin = (c & 7) * 8;
            const u16* g = BmT + ((size_t)n * KTOT + k0 + kin);
            char* l = (char*)Blds + (size_t)(i * 512 + (tid & ~63)) * 16;
            __builtin_amdgcn_global_load_lds((gvoid_t*)g, (lvoid_t*)l, 16, 0, 0);
        }
        __syncthreads();

#pragma unroll
        for (int kk = 0; kk < 2; ++kk) {
            short8 af[4], bfr[4];
#pragma unroll
            for (int mi = 0; mi < 4; ++mi) {
                int r = wr * 64 + mi * 16 + (lane & 15);
                af[mi] = *(const short8*)(Alds + r * BK + kk * 32 + ((lane >> 4) * 8));
            }
#pragma unroll
            for (int ni = 0; ni < 4; ++ni) {
                int ccol = wc * 64 + ni * 16 + (lane & 15);
                bfr[ni] = *(const short8*)(Blds + ccol * BK + kk * 32 + ((lane >> 4) * 8));
            }
#pragma unroll
            for (int mi = 0; mi < 4; ++mi)
#pragma unroll
                for (int ni = 0; ni < 4; ++ni)
                    acc[mi][ni] = __builtin_amdgcn_mfma_f32_16x16x32_bf16(
                        af[mi], bfr[ni], acc[mi][ni], 0, 0, 0);
        }
        __syncthreads();
    }

    // ---- epilogue: out = acc + corr[b][col]
    const int bidx = m0 >> 12;           // 4096 rows per batch, BM=128 divides it
    const float* corr_b = corr + bidx * DIM;
#pragma unroll
    for (int ni = 0; ni < 4; ++ni) {
        int col = wc * 64 + ni * 16 + (lane & 15);
        float cv = corr_b[col];
#pragma unroll
        for (int mi = 0; mi < 4; ++mi) {
            int rbase = m0 + wr * 64 + mi * 16 + ((lane >> 4) * 4);
#pragma unroll
            for (int j = 0; j < 4; ++j)
                out[(size_t)(rbase + j) * DIM + col] = acc[mi][ni][j] + cv;
        }
    }
}

// ---------------------------------------------------------------------------
extern "C" void kernel_launch(void* const* d_in, const int* in_sizes, int n_in,
                              void* d_out, int out_size, void* d_ws, size_t ws_size,
                              hipStream_t stream) {
    const float* x    = (const float*)d_in[0];
    const float* W1   = (const float*)d_in[1];
    const float* W2   = (const float*)d_in[2];
    const float* bias = (const float*)d_in[3];
    const float* mw   = (const float*)d_in[4];
    float* out = (float*)d_out;

    // ws layout: BmT (256*512*2 = 256KB) | total (16KB) | corr (16KB)
    u16*   BmT   = (u16*)d_ws;
    float* total = (float*)((char*)d_ws + 262144);
    float* corr  = (float*)((char*)d_ws + 262144 + 16384);

    hipMemsetAsync(total, 0, NBATCH * DIM * sizeof(float), stream);
    k_bmat<<<dim3(DIM), dim3(256), 0, stream>>>(W1, W2, (uint32_t*)BmT);
    k_conv<<<dim3(SEQ / TW, NBATCH, 2), dim3(256), 0, stream>>>(
        x, mw, (uint32_t*)d_out, total);
    k_corr<<<dim3(NBATCH), dim3(256), 0, stream>>>(W2, bias, mw, total, corr);
    k_gemm<<<dim3(MTOT / BM), dim3(512), 0, stream>>>(
        (const u16*)d_out, BmT, corr, out);
}